// Round 1
// baseline (643.963 us; speedup 1.0000x reference)
//
#include <hip/hip_runtime.h>

// Problem constants
#define T_STEPS 100
#define BATCH   512
#define D0      700
#define D1      512
#define D2      20
#define M_ROWS  (T_STEPS * BATCH)   // 51200

// Output layout (floats): [s2 (T*B*20) | s1 (T*B*512) | s2 copy (T*B*20)]
#define OFF_S2A 0
#define OFF_S1  (T_STEPS * BATCH * D2)                    // 1,024,000
#define OFF_S2B (OFF_S1 + T_STEPS * BATCH * D1)           // 27,238,400

__device__ __constant__ const float kALPHA = 0.8f;
__device__ __constant__ const float kBETA  = 0.9f;
__device__ __constant__ const float kTHR   = 1.0f;

// ---------------------------------------------------------------------------
// GEMM1: C[M,512] = A[M,700] * W1[512,700]^T   (both row-major, K contiguous)
// 128x128 tile, BK=32, 256 threads, 8x8 microtile.
// ---------------------------------------------------------------------------
constexpr int BM = 128, BN = 128, BK = 32;

__global__ __launch_bounds__(256)
void gemm1_kernel(const float* __restrict__ A, const float* __restrict__ W,
                  float* __restrict__ C) {
    __shared__ float As[BK][BM];
    __shared__ float Ws[BK][BN];

    const int tid  = threadIdx.x;
    const int row0 = blockIdx.x * BM;   // 0..399 * 128
    const int col0 = blockIdx.y * BN;   // 0..3   * 128

    const int tx = tid & 15;            // 16 cols of threads
    const int ty = tid >> 4;            // 16 rows of threads

    float acc[8][8];
#pragma unroll
    for (int i = 0; i < 8; ++i)
#pragma unroll
        for (int j = 0; j < 8; ++j) acc[i][j] = 0.f;

    const int NT = (D0 + BK - 1) / BK;  // 22 (last tile zero-padded)
    for (int kt = 0; kt < NT; ++kt) {
        const int k0 = kt * BK;
        // Stage A-tile and W-tile: each 128 rows x 32 k = 1024 float4; 4/thread.
#pragma unroll
        for (int l = 0; l < 4; ++l) {
            const int f  = tid + l * 256;   // 0..1023
            const int r  = f >> 3;          // 8 float4 per row
            const int c4 = f & 7;
            const int k  = c4 * 4;
            const int gk = k0 + k;

            float4 v, w;
            if (gk + 3 < D0) {
                v = *(const float4*)(A + (size_t)(row0 + r) * D0 + gk);
                w = *(const float4*)(W + (size_t)(col0 + r) * D0 + gk);
            } else {
                const float* ap = A + (size_t)(row0 + r) * D0;
                const float* wp = W + (size_t)(col0 + r) * D0;
                v.x = (gk + 0 < D0) ? ap[gk + 0] : 0.f;
                v.y = (gk + 1 < D0) ? ap[gk + 1] : 0.f;
                v.z = (gk + 2 < D0) ? ap[gk + 2] : 0.f;
                v.w = (gk + 3 < D0) ? ap[gk + 3] : 0.f;
                w.x = (gk + 0 < D0) ? wp[gk + 0] : 0.f;
                w.y = (gk + 1 < D0) ? wp[gk + 1] : 0.f;
                w.z = (gk + 2 < D0) ? wp[gk + 2] : 0.f;
                w.w = (gk + 3 < D0) ? wp[gk + 3] : 0.f;
            }
            As[k + 0][r] = v.x; As[k + 1][r] = v.y;
            As[k + 2][r] = v.z; As[k + 3][r] = v.w;
            Ws[k + 0][r] = w.x; Ws[k + 1][r] = w.y;
            Ws[k + 2][r] = w.z; Ws[k + 3][r] = w.w;
        }
        __syncthreads();

#pragma unroll
        for (int k = 0; k < BK; ++k) {
            float a[8], b[8];
            *(float4*)&a[0] = *(const float4*)&As[k][ty * 8 + 0];
            *(float4*)&a[4] = *(const float4*)&As[k][ty * 8 + 4];
            *(float4*)&b[0] = *(const float4*)&Ws[k][tx * 8 + 0];
            *(float4*)&b[4] = *(const float4*)&Ws[k][tx * 8 + 4];
#pragma unroll
            for (int i = 0; i < 8; ++i)
#pragma unroll
                for (int j = 0; j < 8; ++j)
                    acc[i][j] = fmaf(a[i], b[j], acc[i][j]);
        }
        __syncthreads();
    }

#pragma unroll
    for (int i = 0; i < 8; ++i) {
        float* cp = C + (size_t)(row0 + ty * 8 + i) * D1 + col0 + tx * 8;
        float4 v0 = make_float4(acc[i][0], acc[i][1], acc[i][2], acc[i][3]);
        float4 v1 = make_float4(acc[i][4], acc[i][5], acc[i][6], acc[i][7]);
        *(float4*)(cp + 0) = v0;
        *(float4*)(cp + 4) = v1;
    }
}

// ---------------------------------------------------------------------------
// Scan 1: in-place over pre1 buffer [T, B*512]; each thread owns one neuron.
// ---------------------------------------------------------------------------
__global__ __launch_bounds__(256)
void scan1_kernel(float* __restrict__ buf) {
#pragma clang fp contract(off)
    const int idx = blockIdx.x * blockDim.x + threadIdx.x;  // 0 .. 262143
    const int stride = BATCH * D1;
    float syn = 0.f, mem = 0.f;
    float* p = buf + idx;
    for (int t = 0; t < T_STEPS; ++t) {
        const float pre = p[(size_t)t * stride];
        float a = kALPHA * syn;
        syn = a + pre;
        const float reset = (mem > kTHR) ? 1.f : 0.f;
        float bm = kBETA * mem;
        mem = (bm + syn) * (1.f - reset);
        p[(size_t)t * stride] = (mem > kTHR) ? 1.f : 0.f;
    }
}

// ---------------------------------------------------------------------------
// GEMM2: C[M,20] = S1[M,512] * W2[20,512]^T.  W2 staged in LDS (40 KB).
// 256 threads = 64 rows x 4 k-quarters; shuffle-reduce across the 4.
// ---------------------------------------------------------------------------
__global__ __launch_bounds__(256)
void gemm2_kernel(const float* __restrict__ S1, const float* __restrict__ W2,
                  float* __restrict__ C) {
    __shared__ float Wsh[D2 * D1];  // 10240 floats = 40 KB
    for (int i = threadIdx.x; i < (D2 * D1) / 4; i += 256)
        ((float4*)Wsh)[i] = ((const float4*)W2)[i];
    __syncthreads();

    const int r  = threadIdx.x >> 2;   // 0..63
    const int kq = threadIdx.x & 3;    // k quarter (128 each)
    const int m  = blockIdx.x * 64 + r;

    const float4* src = (const float4*)(S1 + (size_t)m * D1 + kq * 128);
    float acc[D2];
#pragma unroll
    for (int o = 0; o < D2; ++o) acc[o] = 0.f;

    for (int j = 0; j < 32; ++j) {
        const float4 v = src[j];
        const float* wbase = Wsh + kq * 128 + j * 4;
#pragma unroll
        for (int o = 0; o < D2; ++o) {
            const float4 w = *(const float4*)(wbase + o * D1);
            acc[o] += v.x * w.x + v.y * w.y + v.z * w.z + v.w * w.w;
        }
    }
    // reduce over the 4 k-quarters (consecutive lanes)
#pragma unroll
    for (int o = 0; o < D2; ++o) {
        acc[o] += __shfl_xor(acc[o], 1);
        acc[o] += __shfl_xor(acc[o], 2);
    }
    if (kq == 0) {
        float* cp = C + (size_t)m * D2;
#pragma unroll
        for (int o = 0; o < D2; o += 4)
            *(float4*)(cp + o) = make_float4(acc[o], acc[o + 1], acc[o + 2], acc[o + 3]);
    }
}

// ---------------------------------------------------------------------------
// Scan 2: in-place over pre2 [T, B*20]; also writes the duplicate s2 slot.
// ---------------------------------------------------------------------------
__global__ __launch_bounds__(256)
void scan2_kernel(float* __restrict__ buf, float* __restrict__ dup) {
#pragma clang fp contract(off)
    const int idx = blockIdx.x * blockDim.x + threadIdx.x;  // 0 .. 10239
    const int stride = BATCH * D2;
    float syn = 0.f, mem = 0.f;
    for (int t = 0; t < T_STEPS; ++t) {
        const size_t off = (size_t)t * stride + idx;
        const float pre = buf[off];
        float a = kALPHA * syn;
        syn = a + pre;
        const float reset = (mem > kTHR) ? 1.f : 0.f;
        float bm = kBETA * mem;
        mem = (bm + syn) * (1.f - reset);
        const float s = (mem > kTHR) ? 1.f : 0.f;
        buf[off] = s;
        dup[off] = s;
    }
}

// ---------------------------------------------------------------------------
extern "C" void kernel_launch(void* const* d_in, const int* in_sizes, int n_in,
                              void* d_out, int out_size, void* d_ws, size_t ws_size,
                              hipStream_t stream) {
    const float* x  = (const float*)d_in[0];   // [100, 512, 700]
    const float* W1 = (const float*)d_in[1];   // [512, 700]
    const float* W2 = (const float*)d_in[2];   // [20, 512]
    float* out = (float*)d_out;

    float* s2a = out + OFF_S2A;   // [T,B,20]  (pre2 then s2)
    float* s1  = out + OFF_S1;    // [T,B,512] (pre1 then s1)
    float* s2b = out + OFF_S2B;   // [T,B,20]  duplicate s2

    // 1) pre1 = x @ W1^T  -> s1 slot
    dim3 g1(M_ROWS / BM, D1 / BN);   // 400 x 4
    gemm1_kernel<<<g1, 256, 0, stream>>>(x, W1, s1);

    // 2) scan layer 1 in place (pre1 -> spikes)
    scan1_kernel<<<(BATCH * D1) / 256, 256, 0, stream>>>(s1);

    // 3) pre2 = s1 @ W2^T -> s2a slot
    gemm2_kernel<<<M_ROWS / 64, 256, 0, stream>>>(s1, W2, s2a);

    // 4) scan layer 2 in place + duplicate
    scan2_kernel<<<(BATCH * D2) / 256, 256, 0, stream>>>(s2a, s2b);
}

// Round 2
// 605.102 us; speedup vs baseline: 1.0642x; 1.0642x over previous
//
#include <hip/hip_runtime.h>

// Problem constants
#define T_STEPS 100
#define BATCH   512
#define D0      700
#define D1      512
#define D2      20
#define M_ROWS  (T_STEPS * BATCH)   // 51200

// Output layout (floats): [s2 (T*B*20) | s1 (T*B*512) | s2 copy (T*B*20)]
#define OFF_S2A 0
#define OFF_S1  (T_STEPS * BATCH * D2)                    // 1,024,000
#define OFF_S2B (OFF_S1 + T_STEPS * BATCH * D1)           // 27,238,400

__device__ __constant__ const float kALPHA = 0.8f;
__device__ __constant__ const float kBETA  = 0.9f;
__device__ __constant__ const float kTHR   = 1.0f;

// ---------------------------------------------------------------------------
// GEMM1: C[M,512] = A[M,700] * W1[512,700]^T   (both row-major, K contiguous)
// 128x128 tile, BK=32, 256 threads, 8x8 microtile.
// LDS tiles stored [BK][BM] with a 16B-chunk XOR swizzle:
//   element m of k-row k lives at chunk  (m>>2) ^ (((m>>2)>>3)&3) ^ ((k>>2)&7)
// which makes (verified by hand):
//   - staging writes (transposed b32 scatter)  2 lanes/bank  (free)
//   - B-fragment float4 reads                  2 addrs/slot  (256B minimum)
//   - A-fragment float4 reads                  distinct-slot broadcasts (free)
// ---------------------------------------------------------------------------
constexpr int BM = 128, BN = 128, BK = 32;

// swizzled float index of element m in k-row k (tile row stride = 128 floats)
__device__ __forceinline__ int swz(int k, int m) {
    const int c = m >> 2;
    const int cpos = c ^ ((c >> 3) & 3) ^ ((k >> 2) & 7);
    return k * BM + (cpos << 2) + (m & 3);
}

__global__ __launch_bounds__(256)
void gemm1_kernel(const float* __restrict__ A, const float* __restrict__ W,
                  float* __restrict__ C) {
    __shared__ float As[BK * BM];
    __shared__ float Ws[BK * BN];

    const int tid  = threadIdx.x;
    const int row0 = blockIdx.x * BM;   // 0..399 * 128
    const int col0 = blockIdx.y * BN;   // 0..3   * 128

    const int tx = tid & 15;            // 16 cols of threads
    const int ty = tid >> 4;            // 16 rows of threads

    // precomputed swizzle chunk bases (k-part XORed in inner loop)
    const int ca0 = (2 * ty)     ^ (((2 * ty)     >> 3) & 3);
    const int ca1 = (2 * ty + 1) ^ (((2 * ty + 1) >> 3) & 3);
    const int cb0 = (2 * tx)     ^ (((2 * tx)     >> 3) & 3);
    const int cb1 = (2 * tx + 1) ^ (((2 * tx + 1) >> 3) & 3);

    float acc[8][8];
#pragma unroll
    for (int i = 0; i < 8; ++i)
#pragma unroll
        for (int j = 0; j < 8; ++j) acc[i][j] = 0.f;

    const int NT = (D0 + BK - 1) / BK;  // 22 (last tile zero-padded)
    for (int kt = 0; kt < NT; ++kt) {
        const int k0 = kt * BK;
        // Stage A-tile and W-tile: each 128 rows x 32 k = 1024 float4; 4/thread.
#pragma unroll
        for (int l = 0; l < 4; ++l) {
            const int f  = tid + l * 256;   // 0..1023
            const int r  = f >> 3;          // 8 float4 per row
            const int c4 = f & 7;
            const int k  = c4 * 4;
            const int gk = k0 + k;

            float4 v, w;
            if (gk + 3 < D0) {
                v = *(const float4*)(A + (size_t)(row0 + r) * D0 + gk);
                w = *(const float4*)(W + (size_t)(col0 + r) * D0 + gk);
            } else {
                const float* ap = A + (size_t)(row0 + r) * D0;
                const float* wp = W + (size_t)(col0 + r) * D0;
                v.x = (gk + 0 < D0) ? ap[gk + 0] : 0.f;
                v.y = (gk + 1 < D0) ? ap[gk + 1] : 0.f;
                v.z = (gk + 2 < D0) ? ap[gk + 2] : 0.f;
                v.w = (gk + 3 < D0) ? ap[gk + 3] : 0.f;
                w.x = (gk + 0 < D0) ? wp[gk + 0] : 0.f;
                w.y = (gk + 1 < D0) ? wp[gk + 1] : 0.f;
                w.z = (gk + 2 < D0) ? wp[gk + 2] : 0.f;
                w.w = (gk + 3 < D0) ? wp[gk + 3] : 0.f;
            }
            // transposed scatter into swizzled layout (b32 writes, 2-way max)
            As[swz(k + 0, r)] = v.x; As[swz(k + 1, r)] = v.y;
            As[swz(k + 2, r)] = v.z; As[swz(k + 3, r)] = v.w;
            Ws[swz(k + 0, r)] = w.x; Ws[swz(k + 1, r)] = w.y;
            Ws[swz(k + 2, r)] = w.z; Ws[swz(k + 3, r)] = w.w;
        }
        __syncthreads();

#pragma unroll
        for (int k = 0; k < BK; ++k) {
            const int kx = (k >> 2) & 7;
            const int kb = k * BM;
            float a[8], b[8];
            *(float4*)&a[0] = *(const float4*)&As[kb + ((ca0 ^ kx) << 2)];
            *(float4*)&a[4] = *(const float4*)&As[kb + ((ca1 ^ kx) << 2)];
            *(float4*)&b[0] = *(const float4*)&Ws[kb + ((cb0 ^ kx) << 2)];
            *(float4*)&b[4] = *(const float4*)&Ws[kb + ((cb1 ^ kx) << 2)];
#pragma unroll
            for (int i = 0; i < 8; ++i)
#pragma unroll
                for (int j = 0; j < 8; ++j)
                    acc[i][j] = fmaf(a[i], b[j], acc[i][j]);
        }
        __syncthreads();
    }

#pragma unroll
    for (int i = 0; i < 8; ++i) {
        float* cp = C + (size_t)(row0 + ty * 8 + i) * D1 + col0 + tx * 8;
        float4 v0 = make_float4(acc[i][0], acc[i][1], acc[i][2], acc[i][3]);
        float4 v1 = make_float4(acc[i][4], acc[i][5], acc[i][6], acc[i][7]);
        *(float4*)(cp + 0) = v0;
        *(float4*)(cp + 4) = v1;
    }
}

// ---------------------------------------------------------------------------
// Scan 1: in-place over pre1 buffer [T, B*512]; each thread owns one neuron.
// ---------------------------------------------------------------------------
__global__ __launch_bounds__(256)
void scan1_kernel(float* __restrict__ buf) {
#pragma clang fp contract(off)
    const int idx = blockIdx.x * blockDim.x + threadIdx.x;  // 0 .. 262143
    const int stride = BATCH * D1;
    float syn = 0.f, mem = 0.f;
    float* p = buf + idx;
    for (int t = 0; t < T_STEPS; ++t) {
        const float pre = p[(size_t)t * stride];
        float a = kALPHA * syn;
        syn = a + pre;
        const float reset = (mem > kTHR) ? 1.f : 0.f;
        float bm = kBETA * mem;
        mem = (bm + syn) * (1.f - reset);
        p[(size_t)t * stride] = (mem > kTHR) ? 1.f : 0.f;
    }
}

// ---------------------------------------------------------------------------
// GEMM2: C[M,20] = S1[M,512] * W2[20,512]^T.  W2 staged in LDS (40 KB).
// 256 threads = 64 rows x 4 k-quarters; shuffle-reduce across the 4.
// ---------------------------------------------------------------------------
__global__ __launch_bounds__(256)
void gemm2_kernel(const float* __restrict__ S1, const float* __restrict__ W2,
                  float* __restrict__ C) {
    __shared__ float Wsh[D2 * D1];  // 10240 floats = 40 KB
    for (int i = threadIdx.x; i < (D2 * D1) / 4; i += 256)
        ((float4*)Wsh)[i] = ((const float4*)W2)[i];
    __syncthreads();

    const int r  = threadIdx.x >> 2;   // 0..63
    const int kq = threadIdx.x & 3;    // k quarter (128 each)
    const int m  = blockIdx.x * 64 + r;

    const float4* src = (const float4*)(S1 + (size_t)m * D1 + kq * 128);
    float acc[D2];
#pragma unroll
    for (int o = 0; o < D2; ++o) acc[o] = 0.f;

    for (int j = 0; j < 32; ++j) {
        const float4 v = src[j];
        const float* wbase = Wsh + kq * 128 + j * 4;
#pragma unroll
        for (int o = 0; o < D2; ++o) {
            const float4 w = *(const float4*)(wbase + o * D1);
            acc[o] += v.x * w.x + v.y * w.y + v.z * w.z + v.w * w.w;
        }
    }
    // reduce over the 4 k-quarters (consecutive lanes)
#pragma unroll
    for (int o = 0; o < D2; ++o) {
        acc[o] += __shfl_xor(acc[o], 1);
        acc[o] += __shfl_xor(acc[o], 2);
    }
    if (kq == 0) {
        float* cp = C + (size_t)m * D2;
#pragma unroll
        for (int o = 0; o < D2; o += 4)
            *(float4*)(cp + o) = make_float4(acc[o], acc[o + 1], acc[o + 2], acc[o + 3]);
    }
}

// ---------------------------------------------------------------------------
// Scan 2: in-place over pre2 [T, B*20]; also writes the duplicate s2 slot.
// ---------------------------------------------------------------------------
__global__ __launch_bounds__(256)
void scan2_kernel(float* __restrict__ buf, float* __restrict__ dup) {
#pragma clang fp contract(off)
    const int idx = blockIdx.x * blockDim.x + threadIdx.x;  // 0 .. 10239
    const int stride = BATCH * D2;
    float syn = 0.f, mem = 0.f;
    for (int t = 0; t < T_STEPS; ++t) {
        const size_t off = (size_t)t * stride + idx;
        const float pre = buf[off];
        float a = kALPHA * syn;
        syn = a + pre;
        const float reset = (mem > kTHR) ? 1.f : 0.f;
        float bm = kBETA * mem;
        mem = (bm + syn) * (1.f - reset);
        const float s = (mem > kTHR) ? 1.f : 0.f;
        buf[off] = s;
        dup[off] = s;
    }
}

// ---------------------------------------------------------------------------
extern "C" void kernel_launch(void* const* d_in, const int* in_sizes, int n_in,
                              void* d_out, int out_size, void* d_ws, size_t ws_size,
                              hipStream_t stream) {
    const float* x  = (const float*)d_in[0];   // [100, 512, 700]
    const float* W1 = (const float*)d_in[1];   // [512, 700]
    const float* W2 = (const float*)d_in[2];   // [20, 512]
    float* out = (float*)d_out;

    float* s2a = out + OFF_S2A;   // [T,B,20]  (pre2 then s2)
    float* s1  = out + OFF_S1;    // [T,B,512] (pre1 then s1)
    float* s2b = out + OFF_S2B;   // [T,B,20]  duplicate s2

    // 1) pre1 = x @ W1^T  -> s1 slot
    dim3 g1(M_ROWS / BM, D1 / BN);   // 400 x 4
    gemm1_kernel<<<g1, 256, 0, stream>>>(x, W1, s1);

    // 2) scan layer 1 in place (pre1 -> spikes)
    scan1_kernel<<<(BATCH * D1) / 256, 256, 0, stream>>>(s1);

    // 3) pre2 = s1 @ W2^T -> s2a slot
    gemm2_kernel<<<M_ROWS / 64, 256, 0, stream>>>(s1, W2, s2a);

    // 4) scan layer 2 in place + duplicate
    scan2_kernel<<<(BATCH * D2) / 256, 256, 0, stream>>>(s2a, s2b);
}